// Round 10
// baseline (93.665 us; speedup 1.0000x reference)
//
#include <hip/hip_runtime.h>
#include <hip/hip_bf16.h>
#include <cstddef>
#include <cstdint>

// Direct-conv reformulation of the Winograd reference (validated r1-r9):
// out[b,o,2i+p,2j+q] = bias[o] + sum_{c,y,x} xpad[b,c,2i-1+y,2j-1+x] * Keff[o,c,p,q,y,x]
// Implicit GEMM: M=65536, N=384, K=1024, bf16 MFMA. Round 10 (occupancy restructure):
//  - SINGLE-buffered A LDS (16 KB; compute/ADMA separated by a 2nd barrier) and
//    M_tile=64 (acc 64->32 regs, X-buf 8 rows): total LDS 26.1 KB -> 6 blocks/CU,
//    24 waves/CU, grid 3072 = 12/CU = 2 clean residency rounds (was 3 blk/27%).
//  - steady head-wait vmcnt(4)+lgkmcnt(0); last chunk peeled with vmcnt(0).
//  - bank-residue classes and A XOR-swizzle identical to validated r8 layout.

#define IHW 128
#define CIN 64
#define COUT 96
#define NCK 16
#define P_DW 152             // 2P = 304 = 16 mod 32 (validated residue class)
#define COFF_DW 80           // = 16 mod 32
#define XBUF_DW (8 * P_DW)   // 1216 dw per buffer (8 rows: kk*4+y)
#define ABUF_DW 4096         // 128 rows x 32 dw (K=64), single buffer

typedef __attribute__((ext_vector_type(8))) short short8_t;
typedef __attribute__((ext_vector_type(4))) float floatx4;

__device__ __forceinline__ short bf16r(float f) {
  uint32_t u = __float_as_uint(f);
  uint32_t r = (u + 0x7FFFu + ((u >> 16) & 1u)) >> 16;
  return (short)r;
}

__device__ __forceinline__ uint32_t pk(float lo, float hi) {
  union { __hip_bfloat16 h; unsigned short s; } a, bq;
  a.h = __float2bfloat16(lo);
  bq.h = __float2bfloat16(hi);
  return (uint32_t)a.s | ((uint32_t)bq.s << 16);
}

// ---------------- Keff precompute ----------------
__global__ void keff_kernel(const float* __restrict__ w, short* __restrict__ keff) {
  int idx = blockIdx.x * 256 + threadIdx.x;
  if (idx >= COUT * CIN) return;
  int o = idx / CIN, c = idx % CIN;
  int g = o / 32;

  int perm[4] = {0, 1, 2, 3};
  if (g == 1) { perm[0] = 1; perm[1] = 0; }
  else if (g == 2) { perm[0] = 3; perm[3] = 0; }

  const float H[4][4] = {{1,1,1,1},{1,-1,1,-1},{1,1,-1,-1},{1,-1,-1,1}};
  float S[2][4];
#pragma unroll
  for (int p = 0; p < 2; ++p)
#pragma unroll
    for (int a = 0; a < 4; ++a) {
      bool pos = (g == 1) ? ((p == 0) ? true : (a < 2))
                          : ((p == 0) ? ((a & 1) == 0) : (a < 2));
      S[p][a] = pos ? 1.f : -1.f;
    }

  float wv[4][4];
#pragma unroll
  for (int a = 0; a < 4; ++a)
#pragma unroll
    for (int d = 0; d < 4; ++d) wv[a][d] = w[(o * CIN + c) * 16 + a * 4 + d];

  for (int p = 0; p < 2; ++p)
    for (int q = 0; q < 2; ++q) {
      int n = o * 4 + p * 2 + q;
      for (int y = 0; y < 4; ++y)
        for (int xx = 0; xx < 4; ++xx) {
          float s = 0.f;
#pragma unroll
          for (int a = 0; a < 4; ++a) {
            float ea = S[p][a] * H[a][perm[xx]];
#pragma unroll
            for (int d = 0; d < 4; ++d) s += ea * S[q][d] * H[d][perm[y]] * wv[a][d];
          }
          keff[n * 1024 + c * 16 + y * 4 + xx] = bf16r(s);
        }
    }
}

// ---------------- main conv kernel ----------------
// block: 256 threads = 4 waves (2 M x 2 N). Tile M=64 patches (1 row), N=128.
// grid: 3072 = 8 XCD x (128 mtiles x 3 nblk) -> 12 blocks/CU, 6 resident.
__global__ __launch_bounds__(256) void conv_mfma(const float* __restrict__ x,
                                                 const short* __restrict__ keff,
                                                 const float* __restrict__ bias,
                                                 float* __restrict__ out) {
  __shared__ uint32_t xlds[2 * XBUF_DW];  // 9,728 B
  __shared__ uint32_t alds[ABUF_DW];      // 16,384 B (single buffer)

  const int tid = threadIdx.x;
  const int lane = tid & 63;
  const int wid = tid >> 6;
  const int wavem = wid >> 1;
  const int wn = wid & 1;
  const int l15 = lane & 15;
  const int l4 = lane >> 4;

  // XCD-aware: 3 nblk of a tile + 128 consecutive mtiles per XCD.
  const int hw = blockIdx.x;            // 0..3071
  const int xcd = hw & 7;
  const int r = hw >> 3;                // 0..383
  const int mtile = xcd * 128 + r / 3;  // 0..1023
  const int nblk = r % 3;
  const int b = mtile >> 6;
  const int i = mtile & 63;
  const int gy0 = 2 * i - 1;

  const float* xb = x + (size_t)b * CIN * IHW * IHW;

  // ---- x staging slots (2/thread): slot = c_loc*128 + y*32 + s ----
  int sl_off[2], sl_dw[2], sl_s[2];
  bool sl_ok[2];
#pragma unroll
  for (int it = 0; it < 2; ++it) {
    const int slot = tid + it * 256;     // 0..511
    const int c_loc = slot >> 7;         // 0..3
    const int y = (slot >> 5) & 3;       // 0..3
    const int s = slot & 31;
    const int gy = gy0 + y;
    const bool ok = (unsigned)gy < (unsigned)IHW;
    sl_off[it] = (c_loc * IHW + (ok ? gy : 0)) * IHW + 4 * s;
    sl_dw[it] = ((c_loc >> 1) * 4 + y) * P_DW + (c_loc & 1) * COFF_DW;
    sl_s[it] = s;
    sl_ok[it] = ok;
  }

  // ---- A DMA slots (4/thread): slot = n*8 + u; src unit swizzled u^(n&7) ----
  int aoff[4];
#pragma unroll
  for (int it = 0; it < 4; ++it) {
    const int slot = tid + it * 256;
    const int n = slot >> 3;
    const int u = slot & 7;
    aoff[it] = (nblk * 128 + n) * 1024 + ((u ^ (n & 7)) << 3);
  }

  float4 gv[2];
  float gn[2];
#define ISSUE(ckv)                                                        \
  {                                                                       \
    _Pragma("unroll") for (int it = 0; it < 2; ++it) {                    \
      const float* p = xb + sl_off[it] + (size_t)(ckv) * (4 * IHW * IHW); \
      gv[it] = *reinterpret_cast<const float4*>(p);                       \
      gn[it] = (sl_s[it] < 31) ? p[4] : 0.f;                              \
    }                                                                     \
  }

#define WRITEST(bs)                                                       \
  {                                                                       \
    uint32_t* Bp = xlds + (bs) * XBUF_DW;                                 \
    _Pragma("unroll") for (int it = 0; it < 2; ++it) {                    \
      float4 v = gv[it];                                                  \
      float nx = gn[it];                                                  \
      if (!sl_ok[it]) { v.x = 0.f; v.y = 0.f; v.z = 0.f; v.w = 0.f; nx = 0.f; } \
      const int o = sl_dw[it] + 2 * sl_s[it] + 1;                         \
      Bp[o] = pk(v.y, v.z);                                               \
      Bp[o + 1] = pk(v.w, nx);                                            \
      if (sl_s[it] == 0) Bp[sl_dw[it]] = pk(0.f, v.x);                    \
    }                                                                     \
  }

#define ADMA(ckv)                                                         \
  {                                                                       \
    _Pragma("unroll") for (int it = 0; it < 4; ++it) {                    \
      const short* src = keff + aoff[it] + (ckv) * 64;                    \
      __builtin_amdgcn_global_load_lds(                                   \
          (const __attribute__((address_space(1))) void*)src,             \
          (__attribute__((address_space(3))) void*)                       \
              &alds[(tid + it * 256) * 4],                                \
          16, 0, 0);                                                      \
    }                                                                     \
  }

  union ufrag { short8_t s8; uint32_t u[4]; };

#define COMPUTE(ckv)                                                      \
  {                                                                       \
    const uint32_t* Xp = xlds + ((ckv) & 1) * XBUF_DW;                    \
    _Pragma("unroll") for (int kk = 0; kk < 2; ++kk) {                    \
      short8_t af[4];                                                     \
      _Pragma("unroll") for (int nf = 0; nf < 4; ++nf) {                  \
        const int row = wn * 64 + nf * 16 + l15;                          \
        const int off = row * 32 + ((((kk << 2) | l4) ^ (l15 & 7)) << 2); \
        af[nf] = *reinterpret_cast<const short8_t*>(alds + off);          \
      }                                                                   \
      const int od = cm_dw + kk * (4 * P_DW);                             \
      ufrag xf[2];                                                        \
      _Pragma("unroll") for (int mf = 0; mf < 2; ++mf) {                  \
        const int o = od + mf * 16;                                       \
        xf[mf].u[0] = Xp[o];                                              \
        xf[mf].u[1] = Xp[o + 1];                                          \
        xf[mf].u[2] = Xp[o + P_DW];                                       \
        xf[mf].u[3] = Xp[o + P_DW + 1];                                   \
      }                                                                   \
      __builtin_amdgcn_s_setprio(1);                                      \
      _Pragma("unroll") for (int mf = 0; mf < 2; ++mf)                    \
        _Pragma("unroll") for (int nf = 0; nf < 4; ++nf)                  \
          acc[mf][nf] = __builtin_amdgcn_mfma_f32_16x16x32_bf16(          \
              af[nf], xf[mf].s8, acc[mf][nf], 0, 0, 0);                   \
      __builtin_amdgcn_s_setprio(0);                                      \
    }                                                                     \
  }

  floatx4 acc[2][4];
#pragma unroll
  for (int i2 = 0; i2 < 2; ++i2)
#pragma unroll
    for (int j2 = 0; j2 < 4; ++j2) acc[i2][j2] = (floatx4){0.f, 0.f, 0.f, 0.f};

  float biasr[4];
#pragma unroll
  for (int nf = 0; nf < 4; ++nf) biasr[nf] = bias[nblk * 32 + wn * 16 + nf * 4 + l4];

  // per-lane X read base: rows y0=2*(l4&1), c_sub=l4>>1, col j = wavem*32+mf*16+l15
  const int cm_dw = (2 * (l4 & 1)) * P_DW + (l4 >> 1) * COFF_DW + wavem * 32 + l15;

  // ---- prologue ----
  ISSUE(0);
  ADMA(0);
  WRITEST(0);   // waits gv(0) via data-dep (vmcnt<=4)
  ISSUE(1);

  // ---- main loop: chunks 0..14 ----
  for (int ck = 0; ck < NCK - 1; ++ck) {
    asm volatile("s_waitcnt vmcnt(4) lgkmcnt(0)" ::: "memory");
    __builtin_amdgcn_s_barrier();
    __builtin_amdgcn_sched_barrier(0);

    COMPUTE(ck);

    __builtin_amdgcn_s_barrier();      // all waves done reading alds + xlds[ck&1]
    __builtin_amdgcn_sched_barrier(0);
    ADMA(ck + 1);                       // overwrite single A buffer
    WRITEST((ck + 1) & 1);              // gv(ck+1); WAR deps keep ISSUE after ADMA
    if (ck + 2 < NCK) ISSUE(ck + 2);
  }

  // ---- peeled last chunk (only ADMA(15) outstanding) ----
  asm volatile("s_waitcnt vmcnt(0) lgkmcnt(0)" ::: "memory");
  __builtin_amdgcn_s_barrier();
  __builtin_amdgcn_sched_barrier(0);
  COMPUTE(NCK - 1);

  // ---- epilogue (validated r2 mapping; j = wavem*32 + mf*16 + l15) ----
  const int orow0 = 2 * i;
#pragma unroll
  for (int nf = 0; nf < 4; ++nf) {
    const int o = nblk * 32 + wn * 16 + nf * 4 + l4;
    const float bv = biasr[nf];
    float* obase = out + ((size_t)(b * COUT + o) * IHW + orow0) * IHW;
#pragma unroll
    for (int mf = 0; mf < 2; ++mf) {
      const int col = 2 * (wavem * 32 + mf * 16 + l15);
      float2 s0 = make_float2(acc[mf][nf][0] + bv, acc[mf][nf][1] + bv);
      float2 s1 = make_float2(acc[mf][nf][2] + bv, acc[mf][nf][3] + bv);
      *reinterpret_cast<float2*>(obase + col) = s0;
      *reinterpret_cast<float2*>(obase + IHW + col) = s1;
    }
  }
#undef ISSUE
#undef WRITEST
#undef ADMA
#undef COMPUTE
}

extern "C" void kernel_launch(void* const* d_in, const int* in_sizes, int n_in,
                              void* d_out, int out_size, void* d_ws, size_t ws_size,
                              hipStream_t stream) {
  const float* x = (const float*)d_in[0];
  const float* w = (const float*)d_in[1];
  const float* bias = (const float*)d_in[2];
  float* out = (float*)d_out;
  short* keff = (short*)d_ws;  // 786432 B

  hipLaunchKernelGGL(keff_kernel, dim3(24), dim3(256), 0, stream, w, keff);
  hipLaunchKernelGGL(conv_mfma, dim3(3072), dim3(256), 0, stream, x, keff, bias, out);
}